// Round 1
// baseline (180.563 us; speedup 1.0000x reference)
//
#include <hip/hip_runtime.h>
#include <cstddef>

#define NROWS 8192
#define RA_STR 72   // bf16 LDS row stride: 144B rows -> 16B aligned, bank-balanced

typedef __attribute__((ext_vector_type(8))) short bf16x8;
typedef __attribute__((ext_vector_type(4))) short short4v;
typedef __attribute__((ext_vector_type(4))) float f32x4;

__device__ __forceinline__ short f2bf(float f) {
  unsigned u = __float_as_uint(f);
  u += 0x7fffu + ((u >> 16) & 1u);   // RNE
  return (short)(u >> 16);
}
__device__ __forceinline__ float leaky_f(float v) { return v >= 0.0f ? v : 0.1f * v; }

// ---------------- Kernel 1: MLP encoder: x[8192,256] -> x2[8192,64], s, sq, x2bfT ----
extern "C" __global__ void __launch_bounds__(256)
encoder_kernel(const float* __restrict__ x, const float* __restrict__ W10,
               const float* __restrict__ b10, const float* __restrict__ W11,
               const float* __restrict__ b11, const float* __restrict__ avec,
               float* __restrict__ x2, float* __restrict__ sarr,
               float* __restrict__ sqarr, short* __restrict__ x2bfT) {
  __shared__ float xr[4][256];
  __shared__ float h1[4][128];
  const int t = threadIdx.x;
  const int r0 = blockIdx.x * 4;
#pragma unroll
  for (int r = 0; r < 4; ++r) xr[r][t] = x[(size_t)(r0 + r) * 256 + t];
  __syncthreads();
  if (t < 128) {
    float acc[4];
    const float b = b10[t];
#pragma unroll
    for (int r = 0; r < 4; ++r) acc[r] = b;
    const float* wrow = W10 + t * 256;
    for (int c = 0; c < 256; c += 4) {
      const float4 wv = *(const float4*)(wrow + c);
#pragma unroll
      for (int r = 0; r < 4; ++r) {
        acc[r] = fmaf(wv.x, xr[r][c], acc[r]);
        acc[r] = fmaf(wv.y, xr[r][c + 1], acc[r]);
        acc[r] = fmaf(wv.z, xr[r][c + 2], acc[r]);
        acc[r] = fmaf(wv.w, xr[r][c + 3], acc[r]);
      }
    }
#pragma unroll
    for (int r = 0; r < 4; ++r) h1[r][t] = leaky_f(acc[r]);
  }
  __syncthreads();
  if (t < 64) {
    float acc[4];
    const float b = b11[t];
#pragma unroll
    for (int r = 0; r < 4; ++r) acc[r] = b;
    const float* wrow = W11 + t * 128;
    for (int c = 0; c < 128; c += 4) {
      const float4 wv = *(const float4*)(wrow + c);
#pragma unroll
      for (int r = 0; r < 4; ++r) {
        acc[r] = fmaf(wv.x, h1[r][c], acc[r]);
        acc[r] = fmaf(wv.y, h1[r][c + 1], acc[r]);
        acc[r] = fmaf(wv.z, h1[r][c + 2], acc[r]);
        acc[r] = fmaf(wv.w, h1[r][c + 3], acc[r]);
      }
    }
    const float av = avec[t];
#pragma unroll
    for (int r = 0; r < 4; ++r) {
      const float v = leaky_f(acc[r]);
      x2[(size_t)(r0 + r) * 64 + t] = v;
      x2bfT[(size_t)t * NROWS + r0 + r] = f2bf(v);
      float ps = v * av, pq = v * v;
#pragma unroll
      for (int off = 1; off < 64; off <<= 1) {
        ps += __shfl_xor(ps, off);
        pq += __shfl_xor(pq, off);
      }
      if (t == 0) { sarr[r0 + r] = ps; sqarr[r0 + r] = pq * (1.0f / 64.0f); }
    }
  }
}

// ---------------- Kernel 2: single fused pass over A --------------------------------
// block = 256 thr (4 waves), 64 rows; JSPLIT=4 -> grid 512; per tile: raw = exp(leaky(si-sj))*A,
// partial rowsum/sumsq/wsq in fp32 regs, raw->bf16 LDS, y += raw @ x2 via MFMA.
extern "C" __global__ void __launch_bounds__(256)
fused_attn_kernel(const float* __restrict__ A, const float* __restrict__ sarr,
                  const float* __restrict__ sqarr, const short* __restrict__ x2bfT,
                  float* __restrict__ yp, float* __restrict__ rsp,
                  float* __restrict__ ssp, float* __restrict__ wsp) {
  __shared__ short rawA[64 * RA_STR];
  __shared__ short xbT[64 * RA_STR];
  __shared__ float sj[64];
  __shared__ float sqj[64];

  const int t = threadIdx.x;
  const int bi = blockIdx.x & 127;
  const int js = blockIdx.x >> 7;
  const int i0 = bi * 64;
  const int jbase = js * 2048;
  const int lane = t & 63;
  const int w = t >> 6;

  const int lrb = t >> 4;        // 0..15 (row group for load phase)
  const int lc = (t & 15) * 4;   // col within tile

  float si[4];
#pragma unroll
  for (int p = 0; p < 4; ++p) si[p] = sarr[i0 + lrb + 16 * p];

  float prsum[4] = {0.f, 0.f, 0.f, 0.f};
  float psumsq[4] = {0.f, 0.f, 0.f, 0.f};
  float pwsq[4] = {0.f, 0.f, 0.f, 0.f};

  const int m0 = (w >> 1) * 32;
  const int n0 = (w & 1) * 32;
  const int fr = lane & 15;
  const int fk = (lane >> 4) * 8;

  f32x4 acc[2][2];
#pragma unroll
  for (int fm = 0; fm < 2; ++fm)
#pragma unroll
    for (int fn = 0; fn < 2; ++fn)
      acc[fm][fn] = (f32x4){0.f, 0.f, 0.f, 0.f};

  float4 areg[4];
#pragma unroll
  for (int p = 0; p < 4; ++p)
    areg[p] = *(const float4*)(A + (size_t)(i0 + lrb + 16 * p) * NROWS + jbase + lc);

  for (int tile = 0; tile < 32; ++tile) {
    const int j0 = jbase + tile * 64;
    __syncthreads();   // prev-tile MFMA done reading LDS
    if (t < 64) { sj[t] = sarr[j0 + t]; sqj[t] = sqarr[j0 + t]; }
#pragma unroll
    for (int p = 0; p < 4; ++p) {
      const int d = lrb + 16 * p;
      const short4v v = *(const short4v*)(x2bfT + (size_t)d * NROWS + j0 + lc);
      *(short4v*)(xbT + d * RA_STR + lc) = v;
    }
    __syncthreads();   // staging visible
#pragma unroll
    for (int p = 0; p < 4; ++p) {
      const float s_i = si[p];
      const float4 av = areg[p];
      const float r0v = __expf(leaky_f(s_i - sj[lc + 0])) * av.x;
      const float r1v = __expf(leaky_f(s_i - sj[lc + 1])) * av.y;
      const float r2v = __expf(leaky_f(s_i - sj[lc + 2])) * av.z;
      const float r3v = __expf(leaky_f(s_i - sj[lc + 3])) * av.w;
      prsum[p] += (r0v + r1v) + (r2v + r3v);
      psumsq[p] += (r0v * r0v + r1v * r1v) + (r2v * r2v + r3v * r3v);
      pwsq[p] += r0v * sqj[lc + 0] + r1v * sqj[lc + 1] + r2v * sqj[lc + 2] + r3v * sqj[lc + 3];
      short4v bw;
      bw[0] = f2bf(r0v); bw[1] = f2bf(r1v); bw[2] = f2bf(r2v); bw[3] = f2bf(r3v);
      *(short4v*)(rawA + (lrb + 16 * p) * RA_STR + lc) = bw;
    }
    // prefetch next tile's A slab into registers (hides HBM latency under MFMA)
    {
      const int jn = jbase + ((tile + 1) & 31) * 64;
#pragma unroll
      for (int p = 0; p < 4; ++p)
        areg[p] = *(const float4*)(A + (size_t)(i0 + lrb + 16 * p) * NROWS + jn + lc);
    }
    __syncthreads();   // rawA/partials visible
#pragma unroll
    for (int ks = 0; ks < 2; ++ks) {
      const bf16x8 af0 = *(const bf16x8*)(rawA + (m0 + fr) * RA_STR + ks * 32 + fk);
      const bf16x8 af1 = *(const bf16x8*)(rawA + (m0 + 16 + fr) * RA_STR + ks * 32 + fk);
      const bf16x8 bv0 = *(const bf16x8*)(xbT + (n0 + fr) * RA_STR + ks * 32 + fk);
      const bf16x8 bv1 = *(const bf16x8*)(xbT + (n0 + 16 + fr) * RA_STR + ks * 32 + fk);
      acc[0][0] = __builtin_amdgcn_mfma_f32_16x16x32_bf16(af0, bv0, acc[0][0], 0, 0, 0);
      acc[0][1] = __builtin_amdgcn_mfma_f32_16x16x32_bf16(af0, bv1, acc[0][1], 0, 0, 0);
      acc[1][0] = __builtin_amdgcn_mfma_f32_16x16x32_bf16(af1, bv0, acc[1][0], 0, 0, 0);
      acc[1][1] = __builtin_amdgcn_mfma_f32_16x16x32_bf16(af1, bv1, acc[1][1], 0, 0, 0);
    }
  }

  // reduce per-row partials across the 16 lanes sharing each row
#pragma unroll
  for (int p = 0; p < 4; ++p) {
#pragma unroll
    for (int off = 1; off < 16; off <<= 1) {
      prsum[p] += __shfl_xor(prsum[p], off);
      psumsq[p] += __shfl_xor(psumsq[p], off);
      pwsq[p] += __shfl_xor(pwsq[p], off);
    }
  }
  if ((t & 15) == 0) {
#pragma unroll
    for (int p = 0; p < 4; ++p) {
      const int gi = i0 + lrb + 16 * p;
      rsp[js * NROWS + gi] = prsum[p];
      ssp[js * NROWS + gi] = psumsq[p];
      wsp[js * NROWS + gi] = pwsq[p];
    }
  }

  // write y partial (C/D layout: col = lane&15, row = (lane>>4)*4 + reg)
  float* ypb = yp + (size_t)js * NROWS * 64;
#pragma unroll
  for (int fm = 0; fm < 2; ++fm)
#pragma unroll
    for (int fn = 0; fn < 2; ++fn)
#pragma unroll
      for (int ri = 0; ri < 4; ++ri) {
        const int row = i0 + m0 + fm * 16 + ((lane >> 4) << 2) + ri;
        const int col = n0 + fn * 16 + (lane & 15);
        ypb[(size_t)row * 64 + col] = acc[fm][fn][ri];
      }
}

// ---------------- Kernel 3: combine partials, GNN layer + head, per-row losses ------
extern "C" __global__ void __launch_bounds__(256)
finish_kernel(const float* __restrict__ x2, const float* __restrict__ sqarr,
              const float* __restrict__ yp, const float* __restrict__ rsp,
              const float* __restrict__ ssp, const float* __restrict__ wsp,
              const float* __restrict__ Wg, const float* __restrict__ bg,
              const float* __restrict__ W2, const float* __restrict__ b2,
              float* __restrict__ outp, float* __restrict__ l1c, float* __restrict__ l2c) {
  __shared__ float hbuf[4][64];
  __shared__ float gbuf[4][64];
  const int t = threadIdx.x;
  const int w = t >> 6, lane = t & 63;
  const int i = blockIdx.x * 4 + w;

  float yv = 0.f, rowsum = 0.f, sumsq = 0.f, wsq = 0.f;
#pragma unroll
  for (int p = 0; p < 4; ++p) {
    yv += yp[(size_t)p * NROWS * 64 + (size_t)i * 64 + lane];
    rowsum += rsp[p * NROWS + i];
    sumsq += ssp[p * NROWS + i];
    wsq += wsp[p * NROWS + i];
  }
  const float inv = 1.0f / rowsum;
  hbuf[w][lane] = yv * inv;
  const float xv = x2[(size_t)i * 64 + lane];
  float xy = xv * yv;
#pragma unroll
  for (int off = 1; off < 64; off <<= 1) xy += __shfl_xor(xy, off);
  if (lane == 0) {
    l1c[i] = sqarr[i] + (wsq - (2.0f / 64.0f) * xy) * inv;
    l2c[i] = sumsq * inv * inv;
  }
  __syncthreads();
  float accg = bg[lane];
  {
    const float* wrow = Wg + lane * 64;
#pragma unroll 4
    for (int d = 0; d < 64; ++d) accg = fmaf(wrow[d], hbuf[w][d], accg);
  }
  gbuf[w][lane] = leaky_f(accg);
  __syncthreads();
  if (lane < 32) {
    float acco = b2[lane];
    const float* wrow = W2 + lane * 64;
#pragma unroll 4
    for (int d = 0; d < 64; ++d) acco = fmaf(wrow[d], gbuf[w][d], acco);
    outp[(size_t)i * 32 + lane] = acco;
  }
}

// ---------------- Kernel 4: scalar loss reduction -----------------------------------
extern "C" __global__ void __launch_bounds__(256)
loss_kernel(const float* __restrict__ l1c, const float* __restrict__ l2c,
            float* __restrict__ outp) {
  __shared__ float s1[256], s2[256];
  const int t = threadIdx.x;
  float a1 = 0.f, a2 = 0.f;
  for (int i = t; i < NROWS; i += 256) { a1 += l1c[i]; a2 += l2c[i]; }
  s1[t] = a1; s2[t] = a2;
  __syncthreads();
  for (int off = 128; off > 0; off >>= 1) {
    if (t < off) { s1[t] += s1[t + off]; s2[t] += s2[t + off]; }
    __syncthreads();
  }
  if (t == 0) {
    const float scale = 1.0f / ((float)NROWS * (float)NROWS);
    outp[NROWS * 32] = s1[0] * scale;
    outp[NROWS * 32 + 1] = s2[0] * scale;
  }
}

// ---------------- launch ------------------------------------------------------------
extern "C" void kernel_launch(void* const* d_in, const int* in_sizes, int n_in,
                              void* d_out, int out_size, void* d_ws, size_t ws_size,
                              hipStream_t stream) {
  const float* x   = (const float*)d_in[0];
  const float* A   = (const float*)d_in[1];
  const float* W10 = (const float*)d_in[2];
  const float* b10 = (const float*)d_in[3];
  const float* W11 = (const float*)d_in[4];
  const float* b11 = (const float*)d_in[5];
  const float* av  = (const float*)d_in[6];
  const float* Wg  = (const float*)d_in[7];
  const float* bg  = (const float*)d_in[8];
  const float* W2  = (const float*)d_in[9];
  const float* b2  = (const float*)d_in[10];
  float* out = (float*)d_out;

  // workspace layout (~12.1 MB total)
  float* ws    = (float*)d_ws;
  float* x2    = ws;                          // N*64
  float* sarr  = x2 + (size_t)NROWS * 64;     // N
  float* sqarr = sarr + NROWS;                // N
  float* yp    = sqarr + NROWS;               // 4*N*64
  float* rsp   = yp + (size_t)4 * NROWS * 64; // 4*N
  float* ssp   = rsp + 4 * NROWS;             // 4*N
  float* wsp   = ssp + 4 * NROWS;             // 4*N
  float* l1c   = wsp + 4 * NROWS;             // N
  float* l2c   = l1c + NROWS;                 // N
  short* x2bfT = (short*)(l2c + NROWS);       // N*64 bf16 (transposed [64][N])

  hipLaunchKernelGGL(encoder_kernel, dim3(2048), dim3(256), 0, stream,
                     x, W10, b10, W11, b11, av, x2, sarr, sqarr, x2bfT);
  hipLaunchKernelGGL(fused_attn_kernel, dim3(512), dim3(256), 0, stream,
                     A, sarr, sqarr, x2bfT, yp, rsp, ssp, wsp);
  hipLaunchKernelGGL(finish_kernel, dim3(2048), dim3(256), 0, stream,
                     x2, sqarr, yp, rsp, ssp, wsp, Wg, bg, W2, b2, out, l1c, l2c);
  hipLaunchKernelGGL(loss_kernel, dim3(1), dim3(256), 0, stream, l1c, l2c, out);
}